// Round 1
// baseline (1124.580 us; speedup 1.0000x reference)
//
#include <hip/hip_runtime.h>
#include <stdint.h>

typedef unsigned short ushort_t;
typedef __attribute__((ext_vector_type(4))) float f32x4;
typedef __attribute__((ext_vector_type(8))) short s16x8;

#define S1_ELEMS ((size_t)1568*64*512)   // 51,380,224 per q/k/v/x/ao buffer

// ---------- bf16 helpers (RNE, bit tricks; no dependence on __hip_bfloat16 internals)
__device__ __forceinline__ ushort_t f2bf(float f) {
  unsigned u = __builtin_bit_cast(unsigned, f);
  u = u + 0x7fffu + ((u >> 16) & 1u);
  return (ushort_t)(u >> 16);
}
__device__ __forceinline__ float bf2f(ushort_t b) {
  unsigned u = ((unsigned)b) << 16;
  return __builtin_bit_cast(float, u);
}

// ---------- async global->LDS, 16B per lane (dest = uniform base + lane*16)
__device__ __forceinline__ void gl_lds16(const ushort_t* g, ushort_t* l) {
  typedef __attribute__((address_space(1))) void gvoid;
  typedef __attribute__((address_space(3))) void lvoid;
  __builtin_amdgcn_global_load_lds((gvoid*)(ushort_t*)g, (lvoid*)l, 16, 0, 0);
}

// ---------- kernel 1: f32 -> bf16 hi/lo split
__global__ void k_convert(const float* __restrict__ src, ushort_t* __restrict__ hi,
                          ushort_t* __restrict__ lo, long n4) {
  long i = (long)blockIdx.x * blockDim.x + threadIdx.x;
  long stride = (long)gridDim.x * blockDim.x;
  for (; i < n4; i += stride) {
    float4 v = ((const float4*)src)[i];
    ushort4 h, l;
    h.x = f2bf(v.x); l.x = f2bf(v.x - bf2f(h.x));
    h.y = f2bf(v.y); l.y = f2bf(v.y - bf2f(h.y));
    h.z = f2bf(v.z); l.z = f2bf(v.z - bf2f(h.z));
    h.w = f2bf(v.w); l.w = f2bf(v.w - bf2f(h.w));
    ((ushort4*)hi)[i] = h;
    ((ushort4*)lo)[i] = l;
  }
}

// ---------- kernel 2: QKV GEMM. C[m,j] = sum_k x[m,k]*qkv_w[j,k], split 3-term.
// 128x128 tile, BK=32, 4 waves (2x2 of 64x64), mfma_f32_16x16x32_bf16.
// Epilogue scatters to q(h,l), k(h,l), v(h) in [B,H,64,32] layout.
__global__ __launch_bounds__(256) void k_gemm_qkv(
    const ushort_t* __restrict__ xh, const ushort_t* __restrict__ xl,
    const ushort_t* __restrict__ wh, const ushort_t* __restrict__ wl,
    ushort_t* __restrict__ qh, ushort_t* __restrict__ ql,
    ushort_t* __restrict__ kh, ushort_t* __restrict__ kl,
    ushort_t* __restrict__ vh) {
  __shared__ ushort_t lds[4][128*32];  // [Ah, Al, Bh, Bl], 32 KiB
  const int tid = threadIdx.x, w = tid >> 6, lane = tid & 63;
  const int g = lane >> 4, l15 = lane & 15;
  const int bx = blockIdx.x, by = blockIdx.y;
  const int wm = w >> 1, wn = w & 1;

  f32x4 acc[4][4];
  #pragma unroll
  for (int r = 0; r < 4; r++)
    #pragma unroll
    for (int c = 0; c < 4; c++) acc[r][c] = (f32x4){0.f,0.f,0.f,0.f};

  const ushort_t* srcp;
  size_t rb;
  if (w < 2) { srcp = (w == 0) ? xh : xl; rb = (size_t)by * 128; }
  else       { srcp = (w == 2) ? wh : wl; rb = (size_t)bx * 128; }
  const int srow = lane >> 2, sko = (lane & 3) * 8;
  ushort_t* lbuf = &lds[w][0];

  for (int kk = 0; kk < 512; kk += 32) {
    #pragma unroll
    for (int j = 0; j < 8; j++)
      gl_lds16(srcp + (rb + (size_t)(j*16 + srow)) * 512 + kk + sko, lbuf + j*512);
    __syncthreads();

    s16x8 afh[4], afl[4], bfh[4], bfl[4];
    #pragma unroll
    for (int t = 0; t < 4; t++) {
      int ar = wm*64 + t*16 + l15;
      afh[t] = *(const s16x8*)&lds[0][ar*32 + g*8];
      afl[t] = *(const s16x8*)&lds[1][ar*32 + g*8];
      int br = wn*64 + t*16 + l15;
      bfh[t] = *(const s16x8*)&lds[2][br*32 + g*8];
      bfl[t] = *(const s16x8*)&lds[3][br*32 + g*8];
    }
    #pragma unroll
    for (int r = 0; r < 4; r++)
      #pragma unroll
      for (int c = 0; c < 4; c++) {
        acc[r][c] = __builtin_amdgcn_mfma_f32_16x16x32_bf16(afh[r], bfh[c], acc[r][c], 0, 0, 0);
        acc[r][c] = __builtin_amdgcn_mfma_f32_16x16x32_bf16(afl[r], bfh[c], acc[r][c], 0, 0, 0);
        acc[r][c] = __builtin_amdgcn_mfma_f32_16x16x32_bf16(afh[r], bfl[c], acc[r][c], 0, 0, 0);
      }
    __syncthreads();
  }

  #pragma unroll
  for (int r = 0; r < 4; r++)
    #pragma unroll
    for (int c = 0; c < 4; c++)
      #pragma unroll
      for (int j = 0; j < 4; j++) {
        int mrow = by*128 + wm*64 + r*16 + g*4 + j;   // D row = (lane>>4)*4+reg
        int ncol = bx*128 + wn*64 + c*16 + l15;       // D col = lane&15
        float v = acc[r][c][j];
        int sel = ncol >> 9, h = (ncol >> 5) & 15, d = ncol & 31;
        int b = mrow >> 6, n = mrow & 63;
        size_t off = (((size_t)b*16 + h)*64 + n)*32 + d;
        ushort_t hv = f2bf(v);
        if (sel == 0)      { qh[off] = hv; ql[off] = f2bf(v - bf2f(hv)); }
        else if (sel == 1) { kh[off] = hv; kl[off] = f2bf(v - bf2f(hv)); }
        else               { vh[off] = hv; }
      }
}

// ---------- kernel 3: per-(b,h) attention. One wave per head-window.
__global__ __launch_bounds__(256) void k_attn(
    const ushort_t* __restrict__ qh, const ushort_t* __restrict__ ql,
    const ushort_t* __restrict__ kh, const ushort_t* __restrict__ kl,
    const ushort_t* __restrict__ vh,
    const float* __restrict__ table, const int* __restrict__ rel_idx,
    ushort_t* __restrict__ aoh, ushort_t* __restrict__ aol) {
  __shared__ ushort_t plds[4][64*72];  // padded stride 72 -> ~2-way conflicts only
  const int tid = threadIdx.x, w = tid >> 6, lane = tid & 63;
  const int g = lane >> 4, l15 = lane & 15;
  const int gw = blockIdx.x * 4 + w;      // 0 .. 25087
  const int b = gw >> 4, h = gw & 15;
  const size_t base = ((size_t)b*16 + h) * 2048;  // 64*32 elements per (b,h)

  // Q, K fragments: A-layout = row (lane&15), k = (lane>>4)*8+i  -> 16B/lane rows
  s16x8 qfh[4], qfl[4], kfh[4], kfl[4];
  #pragma unroll
  for (int t = 0; t < 4; t++) {
    size_t o = base + (size_t)(t*16 + l15)*32 + g*8;
    qfh[t] = *(const s16x8*)&qh[o];
    qfl[t] = *(const s16x8*)&ql[o];
    kfh[t] = *(const s16x8*)&kh[o];
    kfl[t] = *(const s16x8*)&kl[o];
  }
  // V fragments: B-layout = V[k = kt*32 + g*8+i][d = nt*16 + l15]
  s16x8 vf[2][2];
  #pragma unroll
  for (int kt = 0; kt < 2; kt++)
    #pragma unroll
    for (int nt = 0; nt < 2; nt++)
      #pragma unroll
      for (int i = 0; i < 8; i++)
        vf[kt][nt][i] = (short)vh[base + (size_t)(kt*32 + g*8 + i)*32 + nt*16 + l15];

  // S = Q@K^T (split 3-term)
  f32x4 s[4][4];
  #pragma unroll
  for (int r = 0; r < 4; r++)
    #pragma unroll
    for (int c = 0; c < 4; c++) s[r][c] = (f32x4){0.f,0.f,0.f,0.f};
  #pragma unroll
  for (int r = 0; r < 4; r++)
    #pragma unroll
    for (int c = 0; c < 4; c++) {
      s[r][c] = __builtin_amdgcn_mfma_f32_16x16x32_bf16(qfh[r], kfh[c], s[r][c], 0, 0, 0);
      s[r][c] = __builtin_amdgcn_mfma_f32_16x16x32_bf16(qfl[r], kfh[c], s[r][c], 0, 0, 0);
      s[r][c] = __builtin_amdgcn_mfma_f32_16x16x32_bf16(qfh[r], kfl[c], s[r][c], 0, 0, 0);
    }

  // scale + relative-position bias
  const float invs = 0.17677669529663687f;  // 1/sqrt(32)
  #pragma unroll
  for (int r = 0; r < 4; r++)
    #pragma unroll
    for (int c = 0; c < 4; c++)
      #pragma unroll
      for (int j = 0; j < 4; j++) {
        int rr = r*16 + g*4 + j, cc = c*16 + l15;
        float bv = table[rel_idx[rr*64 + cc]*16 + h];
        s[r][c][j] = s[r][c][j]*invs + bv;
      }

  // softmax over cc (4 in-reg cols x 16 lanes of the same 16-lane group)
  #pragma unroll
  for (int r = 0; r < 4; r++)
    #pragma unroll
    for (int j = 0; j < 4; j++) {
      float mx = fmaxf(fmaxf(s[r][0][j], s[r][1][j]), fmaxf(s[r][2][j], s[r][3][j]));
      mx = fmaxf(mx, __shfl_xor(mx, 1));
      mx = fmaxf(mx, __shfl_xor(mx, 2));
      mx = fmaxf(mx, __shfl_xor(mx, 4));
      mx = fmaxf(mx, __shfl_xor(mx, 8));
      float p0 = __expf(s[r][0][j]-mx), p1 = __expf(s[r][1][j]-mx);
      float p2 = __expf(s[r][2][j]-mx), p3 = __expf(s[r][3][j]-mx);
      float sum = p0 + p1 + p2 + p3;
      sum += __shfl_xor(sum, 1);
      sum += __shfl_xor(sum, 2);
      sum += __shfl_xor(sum, 4);
      sum += __shfl_xor(sum, 8);
      float rv = 1.0f / sum;
      s[r][0][j] = p0*rv; s[r][1][j] = p1*rv; s[r][2][j] = p2*rv; s[r][3][j] = p3*rv;
    }

  // P -> LDS (acc layout) then re-read in A-fragment layout
  ushort_t* P = plds[w];
  #pragma unroll
  for (int r = 0; r < 4; r++)
    #pragma unroll
    for (int c = 0; c < 4; c++)
      #pragma unroll
      for (int j = 0; j < 4; j++) {
        int rr = r*16 + g*4 + j, cc = c*16 + l15;
        P[rr*72 + cc] = f2bf(s[r][c][j]);
      }
  s16x8 pf[4][2];
  #pragma unroll
  for (int ta = 0; ta < 4; ta++)
    #pragma unroll
    for (int kt = 0; kt < 2; kt++)
      pf[ta][kt] = *(const s16x8*)&P[(ta*16 + l15)*72 + kt*32 + g*8];

  // out = P @ V
  f32x4 o[4][2];
  #pragma unroll
  for (int ta = 0; ta < 4; ta++)
    #pragma unroll
    for (int nt = 0; nt < 2; nt++) o[ta][nt] = (f32x4){0.f,0.f,0.f,0.f};
  #pragma unroll
  for (int ta = 0; ta < 4; ta++)
    #pragma unroll
    for (int nt = 0; nt < 2; nt++)
      #pragma unroll
      for (int kt = 0; kt < 2; kt++)
        o[ta][nt] = __builtin_amdgcn_mfma_f32_16x16x32_bf16(pf[ta][kt], vf[kt][nt], o[ta][nt], 0, 0, 0);

  // write attention-out as bf16 hi/lo in [m, h*32+d] layout (m = b*64+n)
  #pragma unroll
  for (int ta = 0; ta < 4; ta++)
    #pragma unroll
    for (int nt = 0; nt < 2; nt++)
      #pragma unroll
      for (int j = 0; j < 4; j++) {
        int rr = ta*16 + g*4 + j, dd = nt*16 + l15;
        size_t mo = ((size_t)b*64 + rr)*512 + h*32 + dd;
        float v = o[ta][nt][j];
        ushort_t hv = f2bf(v);
        aoh[mo] = hv;
        aol[mo] = f2bf(v - bf2f(hv));
      }
}

// ---------- kernel 4: proj GEMM. out[m,j] = sum_k ao[m,k]*proj_w[j,k] + pb[j]
__global__ __launch_bounds__(256) void k_gemm_proj(
    const ushort_t* __restrict__ ah, const ushort_t* __restrict__ al,
    const ushort_t* __restrict__ wh, const ushort_t* __restrict__ wl,
    const float* __restrict__ pb, float* __restrict__ out) {
  __shared__ ushort_t lds[4][128*32];
  const int tid = threadIdx.x, w = tid >> 6, lane = tid & 63;
  const int g = lane >> 4, l15 = lane & 15;
  const int bx = blockIdx.x, by = blockIdx.y;
  const int wm = w >> 1, wn = w & 1;

  f32x4 acc[4][4];
  #pragma unroll
  for (int r = 0; r < 4; r++)
    #pragma unroll
    for (int c = 0; c < 4; c++) acc[r][c] = (f32x4){0.f,0.f,0.f,0.f};

  const ushort_t* srcp;
  size_t rb;
  if (w < 2) { srcp = (w == 0) ? ah : al; rb = (size_t)by * 128; }
  else       { srcp = (w == 2) ? wh : wl; rb = (size_t)bx * 128; }
  const int srow = lane >> 2, sko = (lane & 3) * 8;
  ushort_t* lbuf = &lds[w][0];

  for (int kk = 0; kk < 512; kk += 32) {
    #pragma unroll
    for (int j = 0; j < 8; j++)
      gl_lds16(srcp + (rb + (size_t)(j*16 + srow)) * 512 + kk + sko, lbuf + j*512);
    __syncthreads();

    s16x8 afh[4], afl[4], bfh[4], bfl[4];
    #pragma unroll
    for (int t = 0; t < 4; t++) {
      int ar = wm*64 + t*16 + l15;
      afh[t] = *(const s16x8*)&lds[0][ar*32 + g*8];
      afl[t] = *(const s16x8*)&lds[1][ar*32 + g*8];
      int br = wn*64 + t*16 + l15;
      bfh[t] = *(const s16x8*)&lds[2][br*32 + g*8];
      bfl[t] = *(const s16x8*)&lds[3][br*32 + g*8];
    }
    #pragma unroll
    for (int r = 0; r < 4; r++)
      #pragma unroll
      for (int c = 0; c < 4; c++) {
        acc[r][c] = __builtin_amdgcn_mfma_f32_16x16x32_bf16(afh[r], bfh[c], acc[r][c], 0, 0, 0);
        acc[r][c] = __builtin_amdgcn_mfma_f32_16x16x32_bf16(afl[r], bfh[c], acc[r][c], 0, 0, 0);
        acc[r][c] = __builtin_amdgcn_mfma_f32_16x16x32_bf16(afh[r], bfl[c], acc[r][c], 0, 0, 0);
      }
    __syncthreads();
  }

  #pragma unroll
  for (int r = 0; r < 4; r++)
    #pragma unroll
    for (int c = 0; c < 4; c++)
      #pragma unroll
      for (int j = 0; j < 4; j++) {
        int mrow = by*128 + wm*64 + r*16 + g*4 + j;
        int ncol = bx*128 + wn*64 + c*16 + l15;
        out[(size_t)mrow*512 + ncol] = acc[r][c][j] + pb[ncol];
      }
}

extern "C" void kernel_launch(void* const* d_in, const int* in_sizes, int n_in,
                              void* d_out, int out_size, void* d_ws, size_t ws_size,
                              hipStream_t stream) {
  const float* x      = (const float*)d_in[0];
  const float* qkv_w  = (const float*)d_in[1];
  const float* table  = (const float*)d_in[2];
  const float* proj_w = (const float*)d_in[3];
  const float* proj_b = (const float*)d_in[4];
  const int*   rel_idx = (const int*)d_in[5];

  const size_t S1 = S1_ELEMS;
  // ws layout (ushort elements): kh, kl, vh, xh, xl, wqh, wql, wph, wpl
  const size_t need = (5*S1 + 2*786432 + 2*262144) * sizeof(ushort_t);
  if (ws_size < need) return;  // insufficient scratch — fail loudly via absmax

  ushort_t* kh  = (ushort_t*)d_ws;
  ushort_t* kl  = kh + S1;
  ushort_t* vh  = kl + S1;
  ushort_t* xh  = vh + S1;
  ushort_t* xl  = xh + S1;
  ushort_t* wqh = xl + S1;
  ushort_t* wql = wqh + 786432;
  ushort_t* wph = wql + 786432;
  ushort_t* wpl = wph + 262144;
  // q hi/lo live in d_out (205.5 MB = exactly 2*S1 bf16); consumed before proj writes
  ushort_t* qh  = (ushort_t*)d_out;
  ushort_t* ql  = qh + S1;
  // attention-out aliases xh/xl (x dead after QKV GEMM)
  ushort_t* aoh = xh;
  ushort_t* aol = xl;

  k_convert<<<2048, 256, 0, stream>>>(x, xh, xl, (long)(S1/4));
  k_convert<<<256, 256, 0, stream>>>(qkv_w, wqh, wql, 786432/4);
  k_convert<<<128, 256, 0, stream>>>(proj_w, wph, wpl, 262144/4);
  k_gemm_qkv<<<dim3(12, 784), 256, 0, stream>>>(xh, xl, wqh, wql, qh, ql, kh, kl, vh);
  k_attn<<<6272, 256, 0, stream>>>(qh, ql, kh, kl, vh, table, rel_idx, aoh, aol);
  k_gemm_proj<<<dim3(4, 784), 256, 0, stream>>>(aoh, aol, wph, wpl, proj_b, (float*)d_out);
}

// Round 2
// 751.823 us; speedup vs baseline: 1.4958x; 1.4958x over previous
//
#include <hip/hip_runtime.h>
#include <stdint.h>

typedef unsigned short ushort_t;
typedef __attribute__((ext_vector_type(4))) float f32x4;
typedef __attribute__((ext_vector_type(8))) short s16x8;

#define S1_ELEMS ((size_t)1568*64*512)   // 51,380,224 elements per q/k/v/x/ao buffer

// ---------- bf16 helpers (RNE)
__device__ __forceinline__ ushort_t f2bf(float f) {
  unsigned u = __builtin_bit_cast(unsigned, f);
  u = u + 0x7fffu + ((u >> 16) & 1u);
  return (ushort_t)(u >> 16);
}

// ---------- async global->LDS, 16B per lane (dest = uniform base + lane*16)
__device__ __forceinline__ void gl_lds16(const ushort_t* g, ushort_t* l) {
  typedef __attribute__((address_space(1))) void gvoid;
  typedef __attribute__((address_space(3))) void lvoid;
  __builtin_amdgcn_global_load_lds((gvoid*)(ushort_t*)g, (lvoid*)l, 16, 0, 0);
}

// ---------- kernel 1: f32 -> bf16 (hi only)
__global__ void k_convert_hi(const float* __restrict__ src, ushort_t* __restrict__ hi, long n4) {
  long i = (long)blockIdx.x * blockDim.x + threadIdx.x;
  long stride = (long)gridDim.x * blockDim.x;
  for (; i < n4; i += stride) {
    float4 v = ((const float4*)src)[i];
    ushort4 h;
    h.x = f2bf(v.x); h.y = f2bf(v.y); h.z = f2bf(v.z); h.w = f2bf(v.w);
    ((ushort4*)hi)[i] = h;
  }
}

// ---------- kernel 1b: precompute bias[h][rr][cc] = table[rel_idx[rr,cc]*16+h]
__global__ void k_bias(const float* __restrict__ table, const int* __restrict__ rel_idx,
                       float* __restrict__ bias) {
  int i = blockIdx.x * 256 + threadIdx.x;   // 65536 total
  int h = i >> 12, rc = i & 4095;
  bias[i] = table[rel_idx[rc] * 16 + h];
}

// ---------- kernel 2: QKV GEMM, plain bf16, m97 structure.
// 128x128 tile, BK=64, 4 waves (2x2 of 64x64), fragment-linear LDS (0 conflicts).
__global__ __launch_bounds__(256) void k_gemm_qkv(
    const ushort_t* __restrict__ xh, const ushort_t* __restrict__ wh,
    ushort_t* __restrict__ qh, ushort_t* __restrict__ kh, ushort_t* __restrict__ vt) {
  __shared__ ushort_t lds0[2*8192];   // A buf [16 subtiles x 512], B buf same; 32 KiB
  const int tid = threadIdx.x, w = tid >> 6, lane = tid & 63;
  const int g = lane >> 4, l15 = lane & 15;
  // bijective XCD swizzle: nwg = 9408 = 8*1176
  int flat = blockIdx.x;
  int swz = (flat & 7) * 1176 + (flat >> 3);
  int bx = swz % 12, by = swz / 12;
  const int wm = w >> 1, wn = w & 1;

  f32x4 acc[4][4];
  #pragma unroll
  for (int r = 0; r < 4; r++)
    #pragma unroll
    for (int c = 0; c < 4; c++) acc[r][c] = (f32x4){0.f,0.f,0.f,0.f};

  // staging: 32 subtile-issues (2 bufs x 16), 8 per wave.
  // subtile ti = s*2+u (s=row-block of 16, u=k-sub of 32); lane L covers
  // global row s*16+(L&15), k-chunk u*32+(L>>4)*8 -> LDS slot ti*512 + L*8.
  const ushort_t* sptr[8]; int loff[8];
  #pragma unroll
  for (int q = 0; q < 8; q++) {
    int gq = w*8 + q;
    int buf = gq >> 4, ti = gq & 15, s = ti >> 1, u = ti & 1;
    const ushort_t* src = buf ? wh : xh;
    size_t rb = buf ? (size_t)bx*128 : (size_t)by*128;
    sptr[q] = src + (rb + (size_t)(s*16 + l15))*512 + u*32 + g*8;
    loff[q] = buf*8192 + ti*512;
  }

  for (int kk = 0; kk < 512; kk += 64) {
    #pragma unroll
    for (int q = 0; q < 8; q++) gl_lds16(sptr[q] + kk, lds0 + loff[q]);
    __syncthreads();
    #pragma unroll
    for (int u = 0; u < 2; u++) {
      s16x8 af[4], bf[4];
      #pragma unroll
      for (int t = 0; t < 4; t++) {
        af[t] = *(const s16x8*)&lds0[((wm*4 + t)*2 + u)*512 + lane*8];
        bf[t] = *(const s16x8*)&lds0[8192 + ((wn*4 + t)*2 + u)*512 + lane*8];
      }
      #pragma unroll
      for (int r = 0; r < 4; r++)
        #pragma unroll
        for (int c = 0; c < 4; c++)
          acc[r][c] = __builtin_amdgcn_mfma_f32_16x16x32_bf16(af[r], bf[c], acc[r][c], 0, 0, 0);
    }
    __syncthreads();
  }

  // epilogue: scatter to q[b,h,n,d], k[b,h,n,d], vT[b,h,d,n]
  #pragma unroll
  for (int r = 0; r < 4; r++)
    #pragma unroll
    for (int c = 0; c < 4; c++)
      #pragma unroll
      for (int j = 0; j < 4; j++) {
        int mrow = by*128 + wm*64 + r*16 + g*4 + j;
        int ncol = bx*128 + wn*64 + c*16 + l15;
        int sel = ncol >> 9, h = (ncol >> 5) & 15, d = ncol & 31;
        int b = mrow >> 6, n = mrow & 63;
        ushort_t hv = f2bf(acc[r][c][j]);
        if (sel == 0)      qh[(((size_t)b*16 + h)*64 + n)*32 + d] = hv;
        else if (sel == 1) kh[(((size_t)b*16 + h)*64 + n)*32 + d] = hv;
        else               vt[(((size_t)b*16 + h)*32 + d)*64 + n] = hv;
      }
}

// ---------- kernel 3: per-(b,h) attention, plain bf16, one wave per head-window.
__global__ __launch_bounds__(256) void k_attn(
    const ushort_t* __restrict__ qh, const ushort_t* __restrict__ kh,
    const ushort_t* __restrict__ vt, const float* __restrict__ bias,
    ushort_t* __restrict__ aoh) {
  __shared__ ushort_t plds[4][64*72];
  const int tid = threadIdx.x, w = tid >> 6, lane = tid & 63;
  const int g = lane >> 4, l15 = lane & 15;
  const int gw = blockIdx.x * 4 + w;      // 0 .. 25087
  const int b = gw >> 4, h = gw & 15;
  const size_t base = (size_t)(b*16 + h) * 2048;

  s16x8 qf[4], kf[4];
  #pragma unroll
  for (int t = 0; t < 4; t++) {
    size_t o = base + (size_t)(t*16 + l15)*32 + g*8;
    qf[t] = *(const s16x8*)&qh[o];
    kf[t] = *(const s16x8*)&kh[o];
  }
  // V^T fragments: vf[kt][nt] lane (g,l15) = V[m=kt*32+g*8+i][d=nt*16+l15]
  s16x8 vf[2][2];
  #pragma unroll
  for (int kt = 0; kt < 2; kt++)
    #pragma unroll
    for (int nt = 0; nt < 2; nt++)
      vf[kt][nt] = *(const s16x8*)&vt[base + (size_t)(nt*16 + l15)*64 + kt*32 + g*8];

  // S = Q@K^T
  f32x4 s[4][4];
  #pragma unroll
  for (int r = 0; r < 4; r++)
    #pragma unroll
    for (int c = 0; c < 4; c++) s[r][c] = (f32x4){0.f,0.f,0.f,0.f};
  #pragma unroll
  for (int r = 0; r < 4; r++)
    #pragma unroll
    for (int c = 0; c < 4; c++)
      s[r][c] = __builtin_amdgcn_mfma_f32_16x16x32_bf16(qf[r], kf[c], s[r][c], 0, 0, 0);

  // scale + precomputed relative-position bias
  const float invs = 0.17677669529663687f;  // 1/sqrt(32)
  const float* bh_ = bias + ((size_t)h << 12);
  #pragma unroll
  for (int r = 0; r < 4; r++)
    #pragma unroll
    for (int c = 0; c < 4; c++)
      #pragma unroll
      for (int j = 0; j < 4; j++) {
        int rr = r*16 + g*4 + j, cc = c*16 + l15;
        s[r][c][j] = s[r][c][j]*invs + bh_[rr*64 + cc];
      }

  // softmax over cc (4 in-reg cols x 16 lanes of the same 16-lane group)
  #pragma unroll
  for (int r = 0; r < 4; r++)
    #pragma unroll
    for (int j = 0; j < 4; j++) {
      float mx = fmaxf(fmaxf(s[r][0][j], s[r][1][j]), fmaxf(s[r][2][j], s[r][3][j]));
      mx = fmaxf(mx, __shfl_xor(mx, 1));
      mx = fmaxf(mx, __shfl_xor(mx, 2));
      mx = fmaxf(mx, __shfl_xor(mx, 4));
      mx = fmaxf(mx, __shfl_xor(mx, 8));
      float p0 = __expf(s[r][0][j]-mx), p1 = __expf(s[r][1][j]-mx);
      float p2 = __expf(s[r][2][j]-mx), p3 = __expf(s[r][3][j]-mx);
      float sum = p0 + p1 + p2 + p3;
      sum += __shfl_xor(sum, 1);
      sum += __shfl_xor(sum, 2);
      sum += __shfl_xor(sum, 4);
      sum += __shfl_xor(sum, 8);
      float rv = 1.0f / sum;
      s[r][0][j] = p0*rv; s[r][1][j] = p1*rv; s[r][2][j] = p2*rv; s[r][3][j] = p3*rv;
    }

  // P -> LDS (acc layout, pad 72) then re-read in A-fragment layout
  ushort_t* P = plds[w];
  #pragma unroll
  for (int r = 0; r < 4; r++)
    #pragma unroll
    for (int c = 0; c < 4; c++)
      #pragma unroll
      for (int j = 0; j < 4; j++) {
        int rr = r*16 + g*4 + j, cc = c*16 + l15;
        P[rr*72 + cc] = f2bf(s[r][c][j]);
      }
  s16x8 pf[4][2];
  #pragma unroll
  for (int ta = 0; ta < 4; ta++)
    #pragma unroll
    for (int kt = 0; kt < 2; kt++)
      pf[ta][kt] = *(const s16x8*)&P[(ta*16 + l15)*72 + kt*32 + g*8];

  // out = P @ V
  f32x4 o[4][2];
  #pragma unroll
  for (int ta = 0; ta < 4; ta++)
    #pragma unroll
    for (int nt = 0; nt < 2; nt++) o[ta][nt] = (f32x4){0.f,0.f,0.f,0.f};
  #pragma unroll
  for (int ta = 0; ta < 4; ta++)
    #pragma unroll
    for (int nt = 0; nt < 2; nt++)
      #pragma unroll
      for (int kt = 0; kt < 2; kt++)
        o[ta][nt] = __builtin_amdgcn_mfma_f32_16x16x32_bf16(pf[ta][kt], vf[kt][nt], o[ta][nt], 0, 0, 0);

  // write attention-out bf16 in [m, h*32+d] layout
  #pragma unroll
  for (int ta = 0; ta < 4; ta++)
    #pragma unroll
    for (int nt = 0; nt < 2; nt++)
      #pragma unroll
      for (int j = 0; j < 4; j++) {
        int rr = ta*16 + g*4 + j, dd = nt*16 + l15;
        aoh[((size_t)b*64 + rr)*512 + h*32 + dd] = f2bf(o[ta][nt][j]);
      }
}

// ---------- kernel 4: proj GEMM, plain bf16, + bias, f32 out.
__global__ __launch_bounds__(256) void k_gemm_proj(
    const ushort_t* __restrict__ ah, const ushort_t* __restrict__ wh,
    const float* __restrict__ pb, float* __restrict__ out) {
  __shared__ ushort_t lds0[2*8192];
  const int tid = threadIdx.x, w = tid >> 6, lane = tid & 63;
  const int g = lane >> 4, l15 = lane & 15;
  int flat = blockIdx.x;                    // nwg = 3136 = 8*392
  int swz = (flat & 7) * 392 + (flat >> 3);
  int bx = swz & 3, by = swz >> 2;
  const int wm = w >> 1, wn = w & 1;

  f32x4 acc[4][4];
  #pragma unroll
  for (int r = 0; r < 4; r++)
    #pragma unroll
    for (int c = 0; c < 4; c++) acc[r][c] = (f32x4){0.f,0.f,0.f,0.f};

  const ushort_t* sptr[8]; int loff[8];
  #pragma unroll
  for (int q = 0; q < 8; q++) {
    int gq = w*8 + q;
    int buf = gq >> 4, ti = gq & 15, s = ti >> 1, u = ti & 1;
    const ushort_t* src = buf ? wh : ah;
    size_t rb = buf ? (size_t)bx*128 : (size_t)by*128;
    sptr[q] = src + (rb + (size_t)(s*16 + l15))*512 + u*32 + g*8;
    loff[q] = buf*8192 + ti*512;
  }

  for (int kk = 0; kk < 512; kk += 64) {
    #pragma unroll
    for (int q = 0; q < 8; q++) gl_lds16(sptr[q] + kk, lds0 + loff[q]);
    __syncthreads();
    #pragma unroll
    for (int u = 0; u < 2; u++) {
      s16x8 af[4], bf[4];
      #pragma unroll
      for (int t = 0; t < 4; t++) {
        af[t] = *(const s16x8*)&lds0[((wm*4 + t)*2 + u)*512 + lane*8];
        bf[t] = *(const s16x8*)&lds0[8192 + ((wn*4 + t)*2 + u)*512 + lane*8];
      }
      #pragma unroll
      for (int r = 0; r < 4; r++)
        #pragma unroll
        for (int c = 0; c < 4; c++)
          acc[r][c] = __builtin_amdgcn_mfma_f32_16x16x32_bf16(af[r], bf[c], acc[r][c], 0, 0, 0);
    }
    __syncthreads();
  }

  #pragma unroll
  for (int r = 0; r < 4; r++)
    #pragma unroll
    for (int c = 0; c < 4; c++)
      #pragma unroll
      for (int j = 0; j < 4; j++) {
        int mrow = by*128 + wm*64 + r*16 + g*4 + j;
        int ncol = bx*128 + wn*64 + c*16 + l15;
        out[(size_t)mrow*512 + ncol] = acc[r][c][j] + pb[ncol];
      }
}

extern "C" void kernel_launch(void* const* d_in, const int* in_sizes, int n_in,
                              void* d_out, int out_size, void* d_ws, size_t ws_size,
                              hipStream_t stream) {
  const float* x      = (const float*)d_in[0];
  const float* qkv_w  = (const float*)d_in[1];
  const float* table  = (const float*)d_in[2];
  const float* proj_w = (const float*)d_in[3];
  const float* proj_b = (const float*)d_in[4];
  const int*   rel_idx = (const int*)d_in[5];

  const size_t S1 = S1_ELEMS;
  const size_t need = (4*S1 + 786432 + 262144)*sizeof(ushort_t) + 65536*sizeof(float);
  if (ws_size < need) return;

  ushort_t* qh  = (ushort_t*)d_ws;
  ushort_t* kh  = qh + S1;
  ushort_t* vt  = kh + S1;
  ushort_t* xh  = vt + S1;        // reused as attention-out after QKV GEMM
  ushort_t* wqh = xh + S1;
  ushort_t* wph = wqh + 786432;
  float*    bias = (float*)(wph + 262144);
  ushort_t* aoh = xh;

  k_convert_hi<<<2048, 256, 0, stream>>>(x, xh, (long)(S1/4));
  k_convert_hi<<<768, 256, 0, stream>>>(qkv_w, wqh, 196608);
  k_convert_hi<<<256, 256, 0, stream>>>(proj_w, wph, 65536);
  k_bias<<<256, 256, 0, stream>>>(table, rel_idx, bias);
  k_gemm_qkv<<<9408, 256, 0, stream>>>(xh, wqh, qh, kh, vt);
  k_attn<<<6272, 256, 0, stream>>>(qh, kh, vt, bias, aoh);
  k_gemm_proj<<<3136, 256, 0, stream>>>(aoh, wph, proj_b, (float*)d_out);
}